// Round 1
// baseline (1183.843 us; speedup 1.0000x reference)
//
#include <hip/hip_runtime.h>
#include <hip/hip_bf16.h>
#include <math.h>

// DLRM forward: bottom MLP -> embedding gather + pairwise interaction -> top MLP -> sigmoid
// B=16384, 26 tables x 100000 x 64, bottom 13->512->256->64, top 415->512->256->1.

#define BATCH 16384
#define NTAB 26
#define VOCAB 100000
#define MSPA 64
#define NPAIR 351   // 27*26/2
#define HDIM 415    // 64 + 351

// ---------------- Tiled fp32 GEMM with fused bias + ReLU ----------------
// C[M,N] = act(A[M,K] @ W[K,N] + bias[N]),  M%64==0, N%64==0, any K.
#define BM 64
#define BN 64
#define BK 16

__global__ __launch_bounds__(256) void gemm_bias_relu(
    const float* __restrict__ A, const float* __restrict__ W,
    const float* __restrict__ bias, float* __restrict__ C,
    int M, int K, int N)
{
    __shared__ float As[BK][BM];   // As[k][m]
    __shared__ float Bs[BK][BN];   // Bs[k][n]

    const int tid = threadIdx.x;
    const int tx = tid & 15;        // -> n micro-tile
    const int ty = tid >> 4;        // -> m micro-tile
    const int m0 = blockIdx.y * BM;
    const int n0 = blockIdx.x * BN;

    float acc[4][4] = {};

    // A-staging coords: kk = tid%16, row = tid/16 + 16*r (r=0..3)
    const int a_k = tid & 15;
    const int a_m = tid >> 4;
    // B-staging coords: nn = tid%64, krow = tid/64 + 4*r (r=0..3)
    const int b_n = tid & 63;
    const int b_k = tid >> 6;

    for (int k0 = 0; k0 < K; k0 += BK) {
        // stage A tile (zero-pad k >= K)
        #pragma unroll
        for (int r = 0; r < 4; ++r) {
            int m = a_m + 16 * r;
            int k = k0 + a_k;
            As[a_k][m] = (k < K) ? A[(size_t)(m0 + m) * K + k] : 0.f;
        }
        // stage B tile
        #pragma unroll
        for (int r = 0; r < 4; ++r) {
            int k = b_k + 4 * r;
            int gk = k0 + k;
            Bs[k][b_n] = (gk < K) ? W[(size_t)gk * N + n0 + b_n] : 0.f;
        }
        __syncthreads();

        #pragma unroll
        for (int kk = 0; kk < BK; ++kk) {
            float4 av = *(const float4*)&As[kk][ty * 4];
            float4 bv = *(const float4*)&Bs[kk][tx * 4];
            float a[4] = {av.x, av.y, av.z, av.w};
            float b[4] = {bv.x, bv.y, bv.z, bv.w};
            #pragma unroll
            for (int i = 0; i < 4; ++i)
                #pragma unroll
                for (int j = 0; j < 4; ++j)
                    acc[i][j] += a[i] * b[j];
        }
        __syncthreads();
    }

    // epilogue: bias + relu, float4 stores
    #pragma unroll
    for (int i = 0; i < 4; ++i) {
        int m = m0 + ty * 4 + i;
        int n = n0 + tx * 4;
        float4 bv = *(const float4*)&bias[n];
        float4 o;
        o.x = acc[i][0] + bv.x;
        o.y = acc[i][1] + bv.y;
        o.z = acc[i][2] + bv.z;
        o.w = acc[i][3] + bv.w;
        o.x = o.x > 0.f ? o.x : 0.f;
        o.y = o.y > 0.f ? o.y : 0.f;
        o.z = o.z > 0.f ? o.z : 0.f;
        o.w = o.w > 0.f ? o.w : 0.f;
        *(float4*)&C[(size_t)m * N + n] = o;
    }
}

// ---------------- Fused gather + pairwise interaction ----------------
// One wave per sample. T = [emb rows (26) | d row] staged in LDS (stride 65
// breaks the 64-stride bank aliasing). Writes h[b] = [d (64) | inter (351)].
__global__ __launch_bounds__(256) void interact_kernel(
    const float* __restrict__ d,     // [B][64]
    const int* __restrict__ idx,     // [B][26]
    const float* __restrict__ emb,   // [26][VOCAB][64]
    float* __restrict__ h)           // [B][415]
{
    __shared__ float T[4][27][65];
    const int wave = threadIdx.x >> 6;
    const int lane = threadIdx.x & 63;
    const int b = blockIdx.x * 4 + wave;

    #pragma unroll 2
    for (int t = 0; t < NTAB; ++t) {
        int ix = idx[b * NTAB + t];
        T[wave][t][lane] = emb[((size_t)t * VOCAB + ix) * MSPA + lane];
    }
    float dv = d[(size_t)b * MSPA + lane];
    T[wave][NTAB][lane] = dv;
    h[(size_t)b * HDIM + lane] = dv;
    __syncthreads();

    for (int p = lane; p < NPAIR; p += 64) {
        // row-major tril(-1) ordering: find largest i with i*(i-1)/2 <= p
        int i = 1;
        while (((i + 1) * i) / 2 <= p) ++i;
        int j = p - (i * (i - 1)) / 2;
        const float* ti = T[wave][i];
        const float* tj = T[wave][j];
        float s = 0.f;
        #pragma unroll
        for (int k = 0; k < MSPA; ++k) s += ti[k] * tj[k];
        h[(size_t)b * HDIM + MSPA + p] = s;
    }
}

// ---------------- Final layer: dot(256) + bias + sigmoid ----------------
__global__ __launch_bounds__(256) void final_kernel(
    const float* __restrict__ X,   // [B][256]
    const float* __restrict__ w,   // [256] (Wt2 is 256x1 contiguous)
    const float* __restrict__ b2,  // [1]
    float* __restrict__ out)       // [B]
{
    const int wave = threadIdx.x >> 6;
    const int lane = threadIdx.x & 63;
    const int row = blockIdx.x * 4 + wave;
    const float* x = X + (size_t)row * 256;
    float s = 0.f;
    #pragma unroll
    for (int k = 0; k < 4; ++k) s += x[lane + 64 * k] * w[lane + 64 * k];
    #pragma unroll
    for (int off = 32; off > 0; off >>= 1) s += __shfl_down(s, off, 64);
    if (lane == 0) {
        float z = s + b2[0];
        out[row] = 1.f / (1.f + expf(-z));
    }
}

extern "C" void kernel_launch(void* const* d_in, const int* in_sizes, int n_in,
                              void* d_out, int out_size, void* d_ws, size_t ws_size,
                              hipStream_t stream)
{
    const float* dense = (const float*)d_in[0];
    const int*   sidx  = (const int*)d_in[1];
    const float* emb   = (const float*)d_in[2];
    const float* Wb0   = (const float*)d_in[3];
    const float* bb0   = (const float*)d_in[4];
    const float* Wb1   = (const float*)d_in[5];
    const float* bb1   = (const float*)d_in[6];
    const float* Wb2   = (const float*)d_in[7];
    const float* bb2   = (const float*)d_in[8];
    const float* Wt0   = (const float*)d_in[9];
    const float* bt0   = (const float*)d_in[10];
    const float* Wt1   = (const float*)d_in[11];
    const float* bt1   = (const float*)d_in[12];
    const float* Wt2   = (const float*)d_in[13];
    const float* bt2   = (const float*)d_in[14];

    float* ws   = (float*)d_ws;
    float* x512 = ws;                                  // [B][512] (reused by top)
    float* x256 = x512 + (size_t)BATCH * 512;          // [B][256] (reused by top)
    float* dbuf = x256 + (size_t)BATCH * 256;          // [B][64]
    float* hbuf = dbuf + (size_t)BATCH * 64;           // [B][415]
    // total ~81.7 MB fp32

    // bottom MLP
    gemm_bias_relu<<<dim3(512 / BN, BATCH / BM), 256, 0, stream>>>(dense, Wb0, bb0, x512, BATCH, 13, 512);
    gemm_bias_relu<<<dim3(256 / BN, BATCH / BM), 256, 0, stream>>>(x512, Wb1, bb1, x256, BATCH, 512, 256);
    gemm_bias_relu<<<dim3(64 / BN, BATCH / BM), 256, 0, stream>>>(x256, Wb2, bb2, dbuf, BATCH, 256, 64);

    // gather + interaction -> h
    interact_kernel<<<BATCH / 4, 256, 0, stream>>>(dbuf, sidx, emb, hbuf);

    // top MLP
    gemm_bias_relu<<<dim3(512 / BN, BATCH / BM), 256, 0, stream>>>(hbuf, Wt0, bt0, x512, BATCH, HDIM, 512);
    gemm_bias_relu<<<dim3(256 / BN, BATCH / BM), 256, 0, stream>>>(x512, Wt1, bt1, x256, BATCH, 512, 256);

    // final dot + sigmoid
    final_kernel<<<BATCH / 4, 256, 0, stream>>>(x256, Wt2, bt2, (float*)d_out);
}

// Round 2
// 896.409 us; speedup vs baseline: 1.3207x; 1.3207x over previous
//
#include <hip/hip_runtime.h>
#include <hip/hip_bf16.h>
#include <math.h>

// DLRM forward, bf16-MFMA version.
// bottom: 13->512->256->64 (b0 fp32 VALU, b1/b2 bf16 MFMA)
// interact: gather 26 emb rows + d, 27x27 tril dots (fp32 math, bf16 out)
// top: 415(pad 416)->512->256->1 (t0/t1 bf16 MFMA, final dot fp32)

#define BATCH 16384
#define NTAB 26
#define VOCAB 100000
#define MSPA 64
#define NPAIR 351
#define HPAD 416          // 64 + 351 = 415, padded to 416 (K % 32 == 0)

typedef __bf16 bf16x8 __attribute__((ext_vector_type(8)));
typedef float  f32x4  __attribute__((ext_vector_type(4)));

__device__ __forceinline__ void gload_lds16(const __hip_bfloat16* g, void* lds) {
    __builtin_amdgcn_global_load_lds(
        (const __attribute__((address_space(1))) unsigned int*)g,
        (__attribute__((address_space(3))) unsigned int*)lds, 16, 0, 0);
}

// ---------------- bf16 MFMA GEMM: C = relu(A @ Wt^T + bias) ----------------
// A [M,K] bf16 row-major, Wt [N,K] bf16 row-major (pre-transposed weight),
// C [M,N] OutT. M%128==0, N%128==0, K%32==0. 256 threads, 4 waves, 128x128 tile.
template <typename OutT>
__global__ __launch_bounds__(256) void mfma_gemm(
    const __hip_bfloat16* __restrict__ A, const __hip_bfloat16* __restrict__ Wt,
    const float* __restrict__ bias, OutT* __restrict__ C,
    int M, int N, int K)
{
    __shared__ __hip_bfloat16 As[128 * 32];   // [m][k], k contiguous
    __shared__ __hip_bfloat16 Bs[128 * 32];   // [n][k], k contiguous

    const int tid  = threadIdx.x;
    const int wave = tid >> 6;
    const int lane = tid & 63;
    const int m0 = blockIdx.y * 128;
    const int n0 = blockIdx.x * 128;
    const int wm = (wave & 1) * 64;     // wave quadrant within 128x128
    const int wn = (wave >> 1) * 64;

    f32x4 acc[4][4] = {};

    // staging: wave w covers rows [w*32, w*32+32) of the tile, 2 instrs of 16 rows
    const int srow = wave * 32 + (lane >> 2);
    const int scol = (lane & 3) * 8;
    const __hip_bfloat16* ga = A  + (size_t)(m0 + srow) * K + scol;
    const __hip_bfloat16* gb = Wt + (size_t)(n0 + srow) * K + scol;
    char* as_base = (char*)As + (size_t)(wave * 32) * 64;   // row stride 64 B
    char* bs_base = (char*)Bs + (size_t)(wave * 32) * 64;

    // fragment read pointers
    const __hip_bfloat16* ar = As + (size_t)(wm + (lane & 15)) * 32 + (lane >> 4) * 8;
    const __hip_bfloat16* br = Bs + (size_t)(wn + (lane & 15)) * 32 + (lane >> 4) * 8;

    for (int k0 = 0; k0 < K; k0 += 32) {
        gload_lds16(ga + k0,           as_base);
        gload_lds16(ga + 16 * K + k0,  as_base + 1024);
        gload_lds16(gb + k0,           bs_base);
        gload_lds16(gb + 16 * K + k0,  bs_base + 1024);
        __syncthreads();

        bf16x8 af[4], bf[4];
        #pragma unroll
        for (int i = 0; i < 4; ++i) af[i] = *(const bf16x8*)(ar + i * 16 * 32);
        #pragma unroll
        for (int j = 0; j < 4; ++j) bf[j] = *(const bf16x8*)(br + j * 16 * 32);
        #pragma unroll
        for (int i = 0; i < 4; ++i)
            #pragma unroll
            for (int j = 0; j < 4; ++j)
                acc[i][j] = __builtin_amdgcn_mfma_f32_16x16x32_bf16(af[i], bf[j], acc[i][j], 0, 0, 0);
        __syncthreads();
    }

    // epilogue: C/D layout col=lane&15, row=(lane>>4)*4+reg
    #pragma unroll
    for (int j = 0; j < 4; ++j) {
        const int col = n0 + wn + j * 16 + (lane & 15);
        const float bv = bias[col];
        #pragma unroll
        for (int i = 0; i < 4; ++i) {
            const int row = m0 + wm + i * 16 + (lane >> 4) * 4;
            #pragma unroll
            for (int r = 0; r < 4; ++r) {
                float v = acc[i][j][r] + bv;
                v = v > 0.f ? v : 0.f;
                if constexpr (sizeof(OutT) == 2)
                    C[(size_t)(row + r) * N + col] = (OutT)__float2bfloat16(v);
                else
                    C[(size_t)(row + r) * N + col] = (OutT)v;
            }
        }
    }
}

// ---------------- weight convert/transpose (fp32 [K,N] -> bf16 [Npad,Kpad]) ----
__device__ __forceinline__ void cvt_one(int i, const float* src, __hip_bfloat16* dst,
                                        int K, int N, int Kpad) {
    int n = i / Kpad, k = i - n * Kpad;
    float v = (k < K && n < N) ? src[(size_t)k * N + n] : 0.f;
    dst[i] = __float2bfloat16(v);
}

#define CVT0 131072   // Wb1t 256x512
#define CVT1 32768    // Wb2t 128x256
#define CVT2 212992   // Wt0t 512x416
#define CVT3 131072   // Wt1t 256x512

__global__ __launch_bounds__(256) void convert_weights(
    const float* __restrict__ Wb1, const float* __restrict__ Wb2,
    const float* __restrict__ Wt0, const float* __restrict__ Wt1,
    const float* __restrict__ bb2,
    __hip_bfloat16* Wb1t, __hip_bfloat16* Wb2t,
    __hip_bfloat16* Wt0t, __hip_bfloat16* Wt1t, float* bb2p)
{
    int i = blockIdx.x * 256 + threadIdx.x;
    if (i < CVT0) { cvt_one(i, Wb1, Wb1t, 512, 256, 512); return; }
    i -= CVT0;
    if (i < CVT1) { cvt_one(i, Wb2, Wb2t, 256, 64, 256); return; }
    i -= CVT1;
    if (i < CVT2) { cvt_one(i, Wt0, Wt0t, 415, 512, 416); return; }
    i -= CVT2;
    if (i < CVT3) { cvt_one(i, Wt1, Wt1t, 512, 256, 512); return; }
    i -= CVT3;
    if (i < 128)  { bb2p[i] = (i < 64) ? bb2[i] : 0.f; }
}

// ---------------- bottom layer 0: fp32 VALU (K=13), bf16 out ----------------
__global__ __launch_bounds__(256) void bot0_kernel(
    const float* __restrict__ dense, const float* __restrict__ W,
    const float* __restrict__ bias, __hip_bfloat16* __restrict__ out)
{
    const int idx = blockIdx.x * 256 + threadIdx.x;   // m*512 + n
    const int m = idx >> 9, n = idx & 511;
    float s = bias[n];
    #pragma unroll
    for (int k = 0; k < 13; ++k) s += dense[m * 13 + k] * W[k * 512 + n];
    s = s > 0.f ? s : 0.f;
    out[idx] = __float2bfloat16(s);
}

// ---------------- gather + pairwise interaction -> h bf16 [B,416] ----------
__global__ __launch_bounds__(256) void interact_kernel(
    const float* __restrict__ d,     // [B][128] (padded, cols 0..63 valid)
    const int* __restrict__ idx,     // [B][26]
    const float* __restrict__ emb,   // [26][VOCAB][64]
    __hip_bfloat16* __restrict__ h)  // [B][416]
{
    __shared__ float T[4][27][65];
    const int wave = threadIdx.x >> 6;
    const int lane = threadIdx.x & 63;
    const int b = blockIdx.x * 4 + wave;

    #pragma unroll 2
    for (int t = 0; t < NTAB; ++t) {
        int ix = idx[b * NTAB + t];
        T[wave][t][lane] = emb[((size_t)t * VOCAB + ix) * MSPA + lane];
    }
    float dv = d[(size_t)b * 128 + lane];
    T[wave][NTAB][lane] = dv;
    h[(size_t)b * HPAD + lane] = __float2bfloat16(dv);
    if (lane == 0) h[(size_t)b * HPAD + 415] = __float2bfloat16(0.f);
    __syncthreads();

    for (int p = lane; p < NPAIR; p += 64) {
        int i = 1;
        while (((i + 1) * i) / 2 <= p) ++i;
        int j = p - (i * (i - 1)) / 2;
        const float* ti = T[wave][i];
        const float* tj = T[wave][j];
        float s = 0.f;
        #pragma unroll
        for (int k = 0; k < MSPA; ++k) s += ti[k] * tj[k];
        h[(size_t)b * HPAD + MSPA + p] = __float2bfloat16(s);
    }
}

// ---------------- final: dot(256) + bias + sigmoid ----------------
__global__ __launch_bounds__(256) void final_kernel(
    const __hip_bfloat16* __restrict__ X,  // [B][256] bf16
    const float* __restrict__ w,           // [256]
    const float* __restrict__ b2, float* __restrict__ out)
{
    const int wave = threadIdx.x >> 6;
    const int lane = threadIdx.x & 63;
    const int row = blockIdx.x * 4 + wave;
    const __hip_bfloat16* x = X + (size_t)row * 256;
    float s = 0.f;
    #pragma unroll
    for (int k = 0; k < 4; ++k)
        s += __bfloat162float(x[lane + 64 * k]) * w[lane + 64 * k];
    #pragma unroll
    for (int off = 32; off > 0; off >>= 1) s += __shfl_down(s, off, 64);
    if (lane == 0) out[row] = 1.f / (1.f + expf(-(s + b2[0])));
}

extern "C" void kernel_launch(void* const* d_in, const int* in_sizes, int n_in,
                              void* d_out, int out_size, void* d_ws, size_t ws_size,
                              hipStream_t stream)
{
    const float* dense = (const float*)d_in[0];
    const int*   sidx  = (const int*)d_in[1];
    const float* emb   = (const float*)d_in[2];
    const float* Wb0   = (const float*)d_in[3];
    const float* bb0   = (const float*)d_in[4];
    const float* Wb1   = (const float*)d_in[5];
    const float* bb1   = (const float*)d_in[6];
    const float* Wb2   = (const float*)d_in[7];
    const float* bb2   = (const float*)d_in[8];
    const float* Wt0   = (const float*)d_in[9];
    const float* bt0   = (const float*)d_in[10];
    const float* Wt1   = (const float*)d_in[11];
    const float* bt1   = (const float*)d_in[12];
    const float* Wt2   = (const float*)d_in[13];
    const float* bt2   = (const float*)d_in[14];

    char* p = (char*)d_ws;
    auto alloc = [&](size_t bytes) { char* r = p; p += (bytes + 255) & ~(size_t)255; return r; };
    __hip_bfloat16* Wb1t = (__hip_bfloat16*)alloc((size_t)CVT0 * 2);
    __hip_bfloat16* Wb2t = (__hip_bfloat16*)alloc((size_t)CVT1 * 2);
    __hip_bfloat16* Wt0t = (__hip_bfloat16*)alloc((size_t)CVT2 * 2);
    __hip_bfloat16* Wt1t = (__hip_bfloat16*)alloc((size_t)CVT3 * 2);
    float*          bb2p = (float*)alloc(128 * 4);
    __hip_bfloat16* x512 = (__hip_bfloat16*)alloc((size_t)BATCH * 512 * 2);
    __hip_bfloat16* x256 = (__hip_bfloat16*)alloc((size_t)BATCH * 256 * 2);
    float*          dbuf = (float*)alloc((size_t)BATCH * 128 * 4);
    __hip_bfloat16* hbuf = (__hip_bfloat16*)alloc((size_t)BATCH * HPAD * 2);

    // weight convert/transpose (+ padded b2 bias)
    {
        int total = CVT0 + CVT1 + CVT2 + CVT3 + 128;
        convert_weights<<<(total + 255) / 256, 256, 0, stream>>>(
            Wb1, Wb2, Wt0, Wt1, bb2, Wb1t, Wb2t, Wt0t, Wt1t, bb2p);
    }

    // bottom MLP
    bot0_kernel<<<BATCH * 512 / 256, 256, 0, stream>>>(dense, Wb0, bb0, x512);
    mfma_gemm<__hip_bfloat16><<<dim3(256 / 128, BATCH / 128), 256, 0, stream>>>(
        x512, Wb1t, bb1, x256, BATCH, 256, 512);
    mfma_gemm<float><<<dim3(128 / 128, BATCH / 128), 256, 0, stream>>>(
        x256, Wb2t, bb2p, dbuf, BATCH, 128, 256);

    // gather + interaction
    interact_kernel<<<BATCH / 4, 256, 0, stream>>>(dbuf, sidx, emb, hbuf);

    // top MLP
    mfma_gemm<__hip_bfloat16><<<dim3(512 / 128, BATCH / 128), 256, 0, stream>>>(
        hbuf, Wt0t, bt0, x512, BATCH, 512, HPAD);
    mfma_gemm<__hip_bfloat16><<<dim3(256 / 128, BATCH / 128), 256, 0, stream>>>(
        x512, Wt1t, bt1, x256, BATCH, 256, 512);

    // final
    final_kernel<<<BATCH / 4, 256, 0, stream>>>(x256, Wt2, bt2, (float*)d_out);
}